// Round 9
// baseline (260.960 us; speedup 1.0000x reference)
//
#include <hip/hip_runtime.h>

constexpr int kNumItems = 1000000;
constexpr int kXCD = 8;
// ---- fast-path config ----
constexpr int K2     = 256;    // buckets: item >> 12
constexpr int BSH    = 12;
constexpr int BITEMS = 4096;   // items per bucket (256*4096 >= 1M)
constexpr int P      = 512;    // chunks
constexpr int CHUNK  = 16384;  // P*CHUNK = 2^23 = B
constexpr int SBLK   = 512;    // scatter block threads
constexpr int CSTG   = 48;     // staging slots/bucket (multiple of 16)
constexpr int CAP    = 128;    // fixed slot per (block,bucket): mean 64 + 8 sigma
constexpr unsigned kCntShift = 26;
constexpr unsigned kFixMask  = (1u << 26) - 1u;
#define EPSF 1e-10f
#define FIX19 524288.0f            // 2^19 fixed-point rating scale
#define INV_FIX19 (1.0f / 524288.0f)

typedef int   __attribute__((ext_vector_type(4))) intv4;
typedef float __attribute__((ext_vector_type(4))) floatv4;

struct Scalars {
    double sum_avg;
    double n_seen;
};

// ---------------------------------------------------------------------------
// Session lessons (keep; these shaped the structure):
//  * R2: atomicAdd-WITH-RETURN over 256 hot global addresses = serial
//    cross-XCD round-trip chain (462us). No atomic returns on hot paths.
//  * R3: pred at 32 elems/thread spilled (VGPR 44, WRITE 51->116MB), 120us.
//    16 elems/thread (VGPR ~28) is the MLP sweet spot.
//  * R5: L1-bypass gathers in pred: neutral. pred ~70us is L2/L3-side
//    random-line throughput, not L1 miss tracking.
//  * R6: fire-and-forget global atomics under streaming churn = write-through
//    storm (WRITE 131MB/pass, 164us/pass). Accumulate in LDS; write each
//    table line exactly once.
//  * R7: per-block f64 atomics to ONE cache line serialize at ~12.5ns each:
//    3907 blocks x 2 atomics = 98us with nothing else busy. Grid-wide scalar
//    reductions: <=O(100) atomic blocks or two-stage plain-store reduction.
//  * R8 analysis: pred = 8.39M random gathers = 121G 64B-line-fills/s
//    (~7.7TB/s L3->L2) — at the Infinity-Cache random-line rate. Structurally
//    parked at ~69us: u16 table doesn't cut LINE count, MLP>16 spills (R3),
//    L1 bypass neutral (R5), sorting targets costs a scatter pass.
// ---------------------------------------------------------------------------

__device__ __forceinline__ unsigned xcd_id() {
    return __builtin_amdgcn_s_getreg((31u << 11) | 20u) & 7u;
}

__device__ __forceinline__ double blockReduceSum(double v) {
    for (int off = 32; off > 0; off >>= 1)
        v += __shfl_down(v, off, 64);
    __shared__ double s[16];
    __syncthreads();
    const int lane = threadIdx.x & 63;
    const int wave = threadIdx.x >> 6;
    if (lane == 0) s[wave] = v;
    __syncthreads();
    const int nwaves = (blockDim.x + 63) >> 6;
    v = (threadIdx.x < nwaves) ? s[threadIdx.x] : 0.0;
    if (wave == 0) {
        for (int off = 8; off > 0; off >>= 1)
            v += __shfl_down(v, off, 64);
    }
    return v;
}

// pair layout: idx[31:20] (item within bucket) | countbit[19] | fix[18:0]
// zero pair == no-op (add decodes to 0), so zero padding is harmless.
__device__ __forceinline__ unsigned pack_pair(int item, float r) {
    unsigned fix = (unsigned)(r * FIX19);          // r in [0,1): fits 19 bits
    unsigned cb  = (r > 0.0f) ? (1u << 19) : 0u;
    return ((unsigned)(item & (BITEMS - 1)) << 20) | cb | fix;
}

// LDS write-combining scatter, SOFTWARE-PIPELINED (R9): round j+1's global
// loads are issued before consuming round j, so HBM latency (~700cy) hides
// under the LDS staging + flush phases instead of serializing inside the
// barrier-locked round. Flush stores are nontemporal (pairs are write-once;
// keep L2 for the input stream). Block 0 zeroes sc (saves a memset dispatch).
__global__ void scatter_kernel(const int* __restrict__ item,
                               const float* __restrict__ rating,
                               unsigned* __restrict__ cnt,
                               unsigned* __restrict__ pairs, int B,
                               Scalars* sc) {
    __shared__ unsigned stage[K2][CSTG];   // 48KB
    __shared__ unsigned fill[K2];
    __shared__ unsigned flushed[K2];       // 16-groups flushed
    const int p = blockIdx.x;
    if (p == 0 && threadIdx.x == 0) {      // ordered before merge_stats
        sc->sum_avg = 0.0;
        sc->n_seen = 0.0;
    }
    for (int k = threadIdx.x; k < K2; k += SBLK) {
        fill[k] = 0;
        flushed[k] = 0;
    }
    __syncthreads();
    const int base = p * CHUNK;
    const int f16 = threadIdx.x >> 4;      // 32 flushers of 16 lanes
    const int lane16 = threadIdx.x & 15;
    constexpr int ROUNDS = CHUNK / (SBLK * 4);   // 8
    // prologue: load round 0
    int e = base + threadIdx.x * 4;
    intv4 itc; floatv4 rc;
    bool okc = (e + 3 < B);
    if (okc) {
        itc = __builtin_nontemporal_load((const intv4*)(item + e));
        rc  = __builtin_nontemporal_load((const floatv4*)(rating + e));
    }
#pragma unroll 1
    for (int j = 0; j < ROUNDS; ++j) {
        // issue next round's loads FIRST (they fly under staging + flush)
        const int en = e + SBLK * 4;
        intv4 itn; floatv4 rn;
        const bool okn = (j + 1 < ROUNDS) && (en + 3 < B);
        if (okn) {
            itn = __builtin_nontemporal_load((const intv4*)(item + en));
            rn  = __builtin_nontemporal_load((const floatv4*)(rating + en));
        }
        // consume current round
        if (okc) {
            int k; unsigned s;
            k = itc.x >> BSH; s = atomicAdd(&fill[k], 1u); stage[k][s % CSTG] = pack_pair(itc.x, rc.x);
            k = itc.y >> BSH; s = atomicAdd(&fill[k], 1u); stage[k][s % CSTG] = pack_pair(itc.y, rc.y);
            k = itc.z >> BSH; s = atomicAdd(&fill[k], 1u); stage[k][s % CSTG] = pack_pair(itc.z, rc.z);
            k = itc.w >> BSH; s = atomicAdd(&fill[k], 1u); stage[k][s % CSTG] = pack_pair(itc.w, rc.w);
        } else {
            for (int q = e; q < B && q < e + 4; ++q) {
                int k = item[q] >> BSH;
                unsigned s = atomicAdd(&fill[k], 1u);
                stage[k][s % CSTG] = pack_pair(item[q], rating[q]);
            }
        }
        __syncthreads();
        // flush all complete 16-groups (leftover < 16 per bucket afterwards).
        // groups beyond CAP are consumed from the ring but dropped (~never).
        for (int b = 0; b < K2 / 32; ++b) {
            int k = f16 + (b << 5);
            unsigned f = fill[k];
            unsigned g = flushed[k];
            size_t rb = ((size_t)k * P + p) * CAP;
            while ((g + 1) * 16 <= f) {
                unsigned sbase = (g * 16) % CSTG;     // {0,16,32}: no wrap
                unsigned v = stage[k][sbase + lane16];
                if (g * 16 < (unsigned)CAP)
                    __builtin_nontemporal_store(v, pairs + rb + g * 16 + lane16);
                ++g;
            }
            if (lane16 == 0) flushed[k] = g;
        }
        __syncthreads();
        e = en; itc = itn; rc = rn; okc = okn;
    }
    // final partial group, zero-padded to 16 (zero pairs are no-ops)
    for (int b = 0; b < K2 / 32; ++b) {
        int k = f16 + (b << 5);
        unsigned f = fill[k];
        unsigned g = flushed[k];
        if (g * 16 < f && g * 16 < (unsigned)CAP) {
            size_t rb = ((size_t)k * P + p) * CAP;
            unsigned sbase = (g * 16) % CSTG;
            unsigned idx = g * 16 + lane16;
            unsigned v = (idx < f) ? stage[k][sbase + lane16] : 0u;
            __builtin_nontemporal_store(v, pairs + rb + idx);
        }
    }
    // per-(k,p) valid counts for the accum prefix reads
    for (int k = threadIdx.x; k < K2; k += SBLK)
        cnt[(size_t)k * P + p] = min(fill[k], (unsigned)CAP);
}

// two blocks per bucket (p-halves): wave-per-segment prefix reads, LDS
// integer histogram (bit-exact), plain coalesced partial-hist write.
// NO global atomics (round-6 lesson).
__global__ void bucket_accum_kernel(const unsigned* __restrict__ pairs,
                                    const unsigned* __restrict__ cnt,
                                    unsigned* __restrict__ partial) {
    __shared__ unsigned hist[BITEMS];      // 16KB
    __shared__ unsigned cnl[P / 2];
    const int k = blockIdx.x >> 1;
    const int h = blockIdx.x & 1;
    for (int i = threadIdx.x; i < BITEMS; i += 1024) hist[i] = 0;
    if (threadIdx.x < P / 2)
        cnl[threadIdx.x] = cnt[(size_t)k * P + h * (P / 2) + threadIdx.x];
    __syncthreads();
    const int wave = threadIdx.x >> 6;
    const int lane = threadIdx.x & 63;
    for (int q = wave; q < P / 2; q += 16) {
        int p = h * (P / 2) + q;
        unsigned n = cnl[q];                       // wave-uniform (broadcast)
        size_t rb = ((size_t)k * P + p) * CAP;
        for (unsigned i = lane; i < n; i += 64) {
            unsigned v = __builtin_nontemporal_load(pairs + rb + i);
            if (v) {
                unsigned add = ((v & (1u << 19)) << 7) | (v & 0x7FFFFu);
                atomicAdd(&hist[v >> 20], add);
            }
        }
    }
    __syncthreads();
    unsigned* dst = partial + ((size_t)h * K2 + k) * BITEMS;
    for (int i = threadIdx.x; i < BITEMS; i += 1024)
        __builtin_nontemporal_store(hist[i], dst + i);
}

// K2 blocks x 1024 threads: sum the two partial halves -> final table
// (written exactly once), fused global-mean partials. Only 512 contended
// atomics total (round-7 lesson: keep atomic blocks O(100)).
__global__ void merge_stats_kernel(const unsigned* __restrict__ partial,
                                   unsigned* __restrict__ table,
                                   Scalars* sc) {
    const int k = blockIdx.x;
    const size_t b0 = (size_t)k * BITEMS;
    double sum = 0.0, ns = 0.0;
    for (int i = threadIdx.x; i < BITEMS; i += 1024) {
        size_t g = b0 + i;
        if (g < (size_t)kNumItems) {
            unsigned e = partial[g] + partial[(size_t)K2 * BITEMS + g];
            table[g] = e;
            unsigned c = e >> kCntShift;
            if (c) {
                float sf = (float)(e & kFixMask) * INV_FIX19;
                sum += (double)(sf / (float)c);
                ns += 1.0;
            }
        }
    }
    sum = blockReduceSum(sum);
    ns  = blockReduceSum(ns);
    if (threadIdx.x == 0) {
        unsafeAtomicAdd(&sc->sum_avg, sum);
        unsafeAtomicAdd(&sc->n_seen, ns);
    }
}

// ---------------- fallback path (small-workspace safety net) ---------------

__global__ void accum_fb_kernel(const float* __restrict__ rating,
                                const int* __restrict__ item,
                                unsigned* __restrict__ tabs,
                                int B, int lo, int hi) {
    unsigned* tab = tabs + (size_t)xcd_id() * kNumItems;
    int i4 = (blockIdx.x * blockDim.x + threadIdx.x) * 4;
    if (i4 + 3 < B) {
        intv4   it = __builtin_nontemporal_load((const intv4*)(item + i4));
        floatv4 r  = __builtin_nontemporal_load((const floatv4*)(rating + i4));
        int k[4] = {it.x, it.y, it.z, it.w};
        float rr[4] = {r.x, r.y, r.z, r.w};
#pragma unroll
        for (int q = 0; q < 4; ++q)
            if (k[q] >= lo && k[q] < hi) {
                unsigned enc = (unsigned)(rr[q] * FIX19) +
                               (rr[q] > 0.0f ? (1u << kCntShift) : 0u);
                __hip_atomic_fetch_add(tab + k[q], enc, __ATOMIC_RELAXED,
                                       __HIP_MEMORY_SCOPE_WORKGROUP);
            }
    } else {
        for (int i = i4; i < B; ++i)
            if (item[i] >= lo && item[i] < hi) {
                unsigned enc = (unsigned)(rating[i] * FIX19) +
                               (rating[i] > 0.0f ? (1u << kCntShift) : 0u);
                __hip_atomic_fetch_add(tab + item[i], enc, __ATOMIC_RELAXED,
                                       __HIP_MEMORY_SCOPE_WORKGROUP);
            }
    }
}

__global__ void merge_fb_kernel(unsigned* __restrict__ tabs, Scalars* sc, int n) {
    int i = blockIdx.x * blockDim.x + threadIdx.x;
    double sum = 0.0, ns = 0.0;
    if (i < n) {
        unsigned long long t = 0;
#pragma unroll
        for (int x = 0; x < kXCD; ++x)
            t += tabs[(size_t)x * kNumItems + i];
        unsigned e = (unsigned)t;
        tabs[i] = e;
        unsigned c = e >> kCntShift;
        if (c) {
            float sf = (float)(e & kFixMask) * INV_FIX19;
            sum = (double)(sf / (float)c);
            ns = 1.0;
        }
    }
    sum = blockReduceSum(sum);
    ns  = blockReduceSum(ns);
    if (threadIdx.x == 0) {
        unsafeAtomicAdd(&sc->sum_avg, sum);
        unsafeAtomicAdd(&sc->n_seen, ns);
    }
}

// ---------------- shared epilogue ------------------------------------------

__device__ __forceinline__ float decode_pred(unsigned e, float gmf) {
    unsigned c = e >> kCntShift;
    float sf = (float)(e & kFixMask) * INV_FIX19;
    return c ? sf / ((float)c + EPSF) : gmf;
}

// 16 targets/thread (proven sweet spot, VGPR ~28): issue all 8 stream loads +
// all 16 table gathers before any use. Loss partial goes to a plain per-block
// store (lossp), NOT a contended atomic (round-7 lesson).
__global__ void pred_kernel(const unsigned* __restrict__ tab,
                            const int* __restrict__ titem,
                            const float* __restrict__ trat,
                            float* __restrict__ out,
                            double* __restrict__ lossp,
                            const Scalars* __restrict__ sc,
                            int T) {
    const float gmf = (float)(sc->sum_avg / fmax(sc->n_seen, 1.0));
    const int t0 = (blockIdx.x * blockDim.x + threadIdx.x) * 16;
    double l = 0.0;
    if (t0 + 15 < T) {
        intv4 it0 = __builtin_nontemporal_load((const intv4*)(titem + t0));
        intv4 it1 = __builtin_nontemporal_load((const intv4*)(titem + t0 + 4));
        intv4 it2 = __builtin_nontemporal_load((const intv4*)(titem + t0 + 8));
        intv4 it3 = __builtin_nontemporal_load((const intv4*)(titem + t0 + 12));
        floatv4 r0 = __builtin_nontemporal_load((const floatv4*)(trat + t0));
        floatv4 r1 = __builtin_nontemporal_load((const floatv4*)(trat + t0 + 4));
        floatv4 r2 = __builtin_nontemporal_load((const floatv4*)(trat + t0 + 8));
        floatv4 r3 = __builtin_nontemporal_load((const floatv4*)(trat + t0 + 12));
        // 16 independent gathers in flight
        unsigned e0  = tab[(unsigned)it0.x];
        unsigned e1  = tab[(unsigned)it0.y];
        unsigned e2  = tab[(unsigned)it0.z];
        unsigned e3  = tab[(unsigned)it0.w];
        unsigned e4  = tab[(unsigned)it1.x];
        unsigned e5  = tab[(unsigned)it1.y];
        unsigned e6  = tab[(unsigned)it1.z];
        unsigned e7  = tab[(unsigned)it1.w];
        unsigned e8  = tab[(unsigned)it2.x];
        unsigned e9  = tab[(unsigned)it2.y];
        unsigned e10 = tab[(unsigned)it2.z];
        unsigned e11 = tab[(unsigned)it2.w];
        unsigned e12 = tab[(unsigned)it3.x];
        unsigned e13 = tab[(unsigned)it3.y];
        unsigned e14 = tab[(unsigned)it3.z];
        unsigned e15 = tab[(unsigned)it3.w];
        floatv4 p0, p1, p2, p3;
        p0.x = decode_pred(e0,  gmf);
        p0.y = decode_pred(e1,  gmf);
        p0.z = decode_pred(e2,  gmf);
        p0.w = decode_pred(e3,  gmf);
        p1.x = decode_pred(e4,  gmf);
        p1.y = decode_pred(e5,  gmf);
        p1.z = decode_pred(e6,  gmf);
        p1.w = decode_pred(e7,  gmf);
        p2.x = decode_pred(e8,  gmf);
        p2.y = decode_pred(e9,  gmf);
        p2.z = decode_pred(e10, gmf);
        p2.w = decode_pred(e11, gmf);
        p3.x = decode_pred(e12, gmf);
        p3.y = decode_pred(e13, gmf);
        p3.z = decode_pred(e14, gmf);
        p3.w = decode_pred(e15, gmf);
        __builtin_nontemporal_store(p0, (floatv4*)(out + t0));
        __builtin_nontemporal_store(p1, (floatv4*)(out + t0 + 4));
        __builtin_nontemporal_store(p2, (floatv4*)(out + t0 + 8));
        __builtin_nontemporal_store(p3, (floatv4*)(out + t0 + 12));
        double d;
        d = (double)p0.x - (double)r0.x; l += d * d;
        d = (double)p0.y - (double)r0.y; l += d * d;
        d = (double)p0.z - (double)r0.z; l += d * d;
        d = (double)p0.w - (double)r0.w; l += d * d;
        d = (double)p1.x - (double)r1.x; l += d * d;
        d = (double)p1.y - (double)r1.y; l += d * d;
        d = (double)p1.z - (double)r1.z; l += d * d;
        d = (double)p1.w - (double)r1.w; l += d * d;
        d = (double)p2.x - (double)r2.x; l += d * d;
        d = (double)p2.y - (double)r2.y; l += d * d;
        d = (double)p2.z - (double)r2.z; l += d * d;
        d = (double)p2.w - (double)r2.w; l += d * d;
        d = (double)p3.x - (double)r3.x; l += d * d;
        d = (double)p3.y - (double)r3.y; l += d * d;
        d = (double)p3.z - (double)r3.z; l += d * d;
        d = (double)p3.w - (double)r3.w; l += d * d;
    } else {
        for (int i = t0; i < T; ++i) {
            float p = decode_pred(tab[(unsigned)titem[i]], gmf);
            out[i] = p;
            double d = (double)p - (double)trat[i];
            l += d * d;
        }
    }
    l = blockReduceSum(l);
    if (threadIdx.x == 0) lossp[blockIdx.x] = l;
}

// single block: reduce per-block loss partials, emit mean loss.
__global__ void finalize_kernel(const double* __restrict__ lossp, int n,
                                float* __restrict__ out_loss, int T) {
    double l = 0.0;
    for (int i = threadIdx.x; i < n; i += 1024)
        l += lossp[i];
    l = blockReduceSum(l);
    if (threadIdx.x == 0)
        out_loss[0] = (float)(l / (double)T);
}

extern "C" void kernel_launch(void* const* d_in, const int* in_sizes, int n_in,
                              void* d_out, int out_size, void* d_ws, size_t ws_size,
                              hipStream_t stream) {
    const float* rating = (const float*)d_in[0];
    const int*   item   = (const int*)d_in[1];
    const int*   titem  = (const int*)d_in[2];
    const float* trat   = (const float*)d_in[3];
    const int B = in_sizes[0];
    const int T = in_sizes[2];
    const int NI = kNumItems;
    const int BLK = 256;
    float* out = (float*)d_out;
    const int gPred = ((T + 15) / 16 + BLK - 1) / BLK;

    // fast-path workspace layout (u32 units)
    size_t u = 0;
    unsigned* pairs   = (unsigned*)d_ws + 0;  u += (size_t)K2 * P * CAP;   // 67MB
    unsigned* cnt     = (unsigned*)d_ws + u;  u += (size_t)K2 * P;         // 512KB
    unsigned* partial = (unsigned*)d_ws + u;  u += (size_t)2 * K2 * BITEMS;// 8.4MB
    unsigned* table   = (unsigned*)d_ws + u;  u += (size_t)NI;             // 4MB
    size_t lp_off = ((u * 4 + 7) / 8) * 8;
    double* lossp = (double*)((char*)d_ws + lp_off);
    size_t sc_off = lp_off + (size_t)gPred * sizeof(double);
    Scalars* sc = (Scalars*)((char*)d_ws + sc_off);
    const size_t needed = sc_off + sizeof(Scalars);

    const bool fast = (ws_size >= needed) && (B <= P * CHUNK);

    if (fast) {
        // sc zeroed by scatter block 0 (no memset dispatch)
        scatter_kernel<<<P, SBLK, 0, stream>>>(item, rating, cnt, pairs, B, sc);
        bucket_accum_kernel<<<2 * K2, 1024, 0, stream>>>(pairs, cnt, partial);
        merge_stats_kernel<<<K2, 1024, 0, stream>>>(partial, table, sc);
        pred_kernel<<<gPred, BLK, 0, stream>>>(table, titem, trat,
                                               out, lossp, sc, T);
        finalize_kernel<<<1, 1024, 0, stream>>>(lossp, gPred, out + T, T);
    } else {
        unsigned* tabs = (unsigned*)d_ws;
        double* lossp2 = (double*)((char*)d_ws +
                                   (size_t)kXCD * NI * sizeof(unsigned));
        Scalars* sc2 = (Scalars*)((char*)lossp2 + (size_t)gPred * sizeof(double));
        (void)hipMemsetAsync(d_ws, 0,
                             (size_t)kXCD * NI * sizeof(unsigned) +
                             (size_t)gPred * sizeof(double) + sizeof(Scalars),
                             stream);
        const int gAcc = ((B + 3) / 4 + BLK - 1) / BLK;
        accum_fb_kernel<<<gAcc, BLK, 0, stream>>>(rating, item, tabs, B, 0, NI / 2);
        accum_fb_kernel<<<gAcc, BLK, 0, stream>>>(rating, item, tabs, B, NI / 2, NI);
        merge_fb_kernel<<<(NI + BLK - 1) / BLK, BLK, 0, stream>>>(tabs, sc2, NI);
        pred_kernel<<<gPred, BLK, 0, stream>>>(tabs, titem, trat,
                                               out, lossp2, sc2, T);
        finalize_kernel<<<1, 1024, 0, stream>>>(lossp2, gPred, out + T, T);
    }
}

// Round 10
// 251.239 us; speedup vs baseline: 1.0387x; 1.0387x over previous
//
#include <hip/hip_runtime.h>

constexpr int kNumItems = 1000000;
constexpr int kXCD = 8;
// ---- fast-path config ----
constexpr int K2     = 256;    // buckets: item >> 12
constexpr int BSH    = 12;
constexpr int BITEMS = 4096;   // items per bucket (256*4096 >= 1M)
constexpr int P      = 512;    // chunks
constexpr int CHUNK  = 16384;  // P*CHUNK = 2^23 = B
constexpr int SBLK   = 512;    // scatter block threads
constexpr int CSTG   = 48;     // staging slots/bucket (multiple of 16)
constexpr int CAP    = 128;    // fixed slot per (block,bucket): mean 64 + 8 sigma
constexpr unsigned kCntShift = 26;
constexpr unsigned kFixMask  = (1u << 26) - 1u;
#define EPSF 1e-10f
#define FIX19 524288.0f            // 2^19 fixed-point rating scale
#define INV_FIX19 (1.0f / 524288.0f)

typedef int   __attribute__((ext_vector_type(4))) intv4;
typedef float __attribute__((ext_vector_type(4))) floatv4;

struct Scalars {
    double sum_avg;
    double n_seen;
};

// ---------------------------------------------------------------------------
// Session lessons (keep; these shaped the structure):
//  * R2: atomicAdd-WITH-RETURN over 256 hot global addresses = serial
//    cross-XCD round-trip chain (462us). No atomic returns on hot paths.
//  * R3: pred at 32 elems/thread spilled (VGPR 44, WRITE 51->116MB), 120us.
//    16 elems/thread (VGPR ~28) is the MLP sweet spot.
//  * R5: L1-bypass gathers in pred: neutral. pred ~70us is L2/L3-side
//    random-line throughput, not L1 miss tracking.
//  * R6: fire-and-forget global atomics under streaming churn = write-through
//    storm (WRITE 131MB/pass, 164us/pass). Accumulate in LDS; write each
//    table line exactly once.
//  * R7: per-block f64 atomics to ONE cache line serialize at ~12.5ns each.
//    Grid-wide scalar reductions: <=O(100) atomic blocks or two-stage
//    plain-store reduction.
//  * R8 analysis: pred = 8.39M random gathers = 121G 64B-line-fills/s
//    (~7.7TB/s L3->L2) — at the Infinity-Cache random-line rate. Structurally
//    parked at ~69us.
//  * R9: (a) software-pipelining scatter loads: neutral (compiler already
//    hoists them); (b) NONTEMPORAL stores on pairs: regression suspect —
//    pairs is re-read by accum immediately; NT evicts from L2/L3 so accum
//    refetches from HBM. NT stores only for write-once-read-never data.
//  * R10: pairs layout transposed to [p][k][CAP] — scatter writes land in a
//    contiguous 128KB per-block window (DRAM-page/L2 write locality);
//    accum reads stay 256B-contiguous per wave.
// ---------------------------------------------------------------------------

__device__ __forceinline__ unsigned xcd_id() {
    return __builtin_amdgcn_s_getreg((31u << 11) | 20u) & 7u;
}

__device__ __forceinline__ double blockReduceSum(double v) {
    for (int off = 32; off > 0; off >>= 1)
        v += __shfl_down(v, off, 64);
    __shared__ double s[16];
    __syncthreads();
    const int lane = threadIdx.x & 63;
    const int wave = threadIdx.x >> 6;
    if (lane == 0) s[wave] = v;
    __syncthreads();
    const int nwaves = (blockDim.x + 63) >> 6;
    v = (threadIdx.x < nwaves) ? s[threadIdx.x] : 0.0;
    if (wave == 0) {
        for (int off = 8; off > 0; off >>= 1)
            v += __shfl_down(v, off, 64);
    }
    return v;
}

// pair layout: idx[31:20] (item within bucket) | countbit[19] | fix[18:0]
// zero pair == no-op (add decodes to 0), so zero padding is harmless.
__device__ __forceinline__ unsigned pack_pair(int item, float r) {
    unsigned fix = (unsigned)(r * FIX19);          // r in [0,1): fits 19 bits
    unsigned cb  = (r > 0.0f) ? (1u << 19) : 0u;
    return ((unsigned)(item & (BITEMS - 1)) << 20) | cb | fix;
}

// LDS write-combining scatter: stage pairs per bucket, flush complete
// 16-element (64B) groups into the block's OWN contiguous 128KB window
// pairs[p][k][CAP] (R10 transposed layout). Block 0 zeroes sc.
__global__ void scatter_kernel(const int* __restrict__ item,
                               const float* __restrict__ rating,
                               unsigned* __restrict__ cnt,
                               unsigned* __restrict__ pairs, int B,
                               Scalars* sc) {
    __shared__ unsigned stage[K2][CSTG];   // 48KB
    __shared__ unsigned fill[K2];
    __shared__ unsigned flushed[K2];       // 16-groups flushed
    const int p = blockIdx.x;
    if (p == 0 && threadIdx.x == 0) {      // ordered before merge_stats
        sc->sum_avg = 0.0;
        sc->n_seen = 0.0;
    }
    for (int k = threadIdx.x; k < K2; k += SBLK) {
        fill[k] = 0;
        flushed[k] = 0;
    }
    __syncthreads();
    const int base = p * CHUNK;
    const int f16 = threadIdx.x >> 4;      // 32 flushers of 16 lanes
    const int lane16 = threadIdx.x & 15;
#pragma unroll 1
    for (int j = 0; j < CHUNK / (SBLK * 4); ++j) {   // 8 rounds x 2048 elems
        int e = base + j * (SBLK * 4) + threadIdx.x * 4;
        if (e + 3 < B) {
            intv4   it = __builtin_nontemporal_load((const intv4*)(item + e));
            floatv4 r  = __builtin_nontemporal_load((const floatv4*)(rating + e));
            int k; unsigned s;
            k = it.x >> BSH; s = atomicAdd(&fill[k], 1u); stage[k][s % CSTG] = pack_pair(it.x, r.x);
            k = it.y >> BSH; s = atomicAdd(&fill[k], 1u); stage[k][s % CSTG] = pack_pair(it.y, r.y);
            k = it.z >> BSH; s = atomicAdd(&fill[k], 1u); stage[k][s % CSTG] = pack_pair(it.z, r.z);
            k = it.w >> BSH; s = atomicAdd(&fill[k], 1u); stage[k][s % CSTG] = pack_pair(it.w, r.w);
        } else {
            for (int q = e; q < B && q < e + 4; ++q) {
                int k = item[q] >> BSH;
                unsigned s = atomicAdd(&fill[k], 1u);
                stage[k][s % CSTG] = pack_pair(item[q], rating[q]);
            }
        }
        __syncthreads();
        // flush all complete 16-groups (leftover < 16 per bucket afterwards).
        // groups beyond CAP are consumed from the ring but dropped (~never).
        for (int b = 0; b < K2 / 32; ++b) {
            int k = f16 + (b << 5);
            unsigned f = fill[k];
            unsigned g = flushed[k];
            size_t rb = ((size_t)p * K2 + k) * CAP;   // R10: block-local window
            while ((g + 1) * 16 <= f) {
                unsigned sbase = (g * 16) % CSTG;     // {0,16,32}: no wrap
                unsigned v = stage[k][sbase + lane16];
                if (g * 16 < (unsigned)CAP)
                    pairs[rb + g * 16 + lane16] = v;
                ++g;
            }
            if (lane16 == 0) flushed[k] = g;
        }
        __syncthreads();
    }
    // final partial group, zero-padded to 16 (zero pairs are no-ops)
    for (int b = 0; b < K2 / 32; ++b) {
        int k = f16 + (b << 5);
        unsigned f = fill[k];
        unsigned g = flushed[k];
        if (g * 16 < f && g * 16 < (unsigned)CAP) {
            size_t rb = ((size_t)p * K2 + k) * CAP;
            unsigned sbase = (g * 16) % CSTG;
            unsigned idx = g * 16 + lane16;
            unsigned v = (idx < f) ? stage[k][sbase + lane16] : 0u;
            pairs[rb + idx] = v;
        }
    }
    // per-(k,p) valid counts for the accum prefix reads
    for (int k = threadIdx.x; k < K2; k += SBLK)
        cnt[(size_t)k * P + p] = min(fill[k], (unsigned)CAP);
}

// two blocks per bucket (p-halves): wave-per-segment prefix reads (256B
// contiguous per wave), LDS integer histogram (bit-exact), plain coalesced
// partial-hist write. NO global atomics (round-6 lesson).
__global__ void bucket_accum_kernel(const unsigned* __restrict__ pairs,
                                    const unsigned* __restrict__ cnt,
                                    unsigned* __restrict__ partial) {
    __shared__ unsigned hist[BITEMS];      // 16KB
    __shared__ unsigned cnl[P / 2];
    const int k = blockIdx.x >> 1;
    const int h = blockIdx.x & 1;
    for (int i = threadIdx.x; i < BITEMS; i += 1024) hist[i] = 0;
    if (threadIdx.x < P / 2)
        cnl[threadIdx.x] = cnt[(size_t)k * P + h * (P / 2) + threadIdx.x];
    __syncthreads();
    const int wave = threadIdx.x >> 6;
    const int lane = threadIdx.x & 63;
    for (int q = wave; q < P / 2; q += 16) {
        int p = h * (P / 2) + q;
        unsigned n = cnl[q];                       // wave-uniform (broadcast)
        size_t rb = ((size_t)p * K2 + k) * CAP;    // R10 transposed layout
        for (unsigned i = lane; i < n; i += 64) {
            unsigned v = __builtin_nontemporal_load(pairs + rb + i);
            if (v) {
                unsigned add = ((v & (1u << 19)) << 7) | (v & 0x7FFFFu);
                atomicAdd(&hist[v >> 20], add);
            }
        }
    }
    __syncthreads();
    unsigned* dst = partial + ((size_t)h * K2 + k) * BITEMS;
    for (int i = threadIdx.x; i < BITEMS; i += 1024)
        __builtin_nontemporal_store(hist[i], dst + i);
}

// K2 blocks x 1024 threads: sum the two partial halves -> final table
// (written exactly once), fused global-mean partials. Only 512 contended
// atomics total (round-7 lesson: keep atomic blocks O(100)).
__global__ void merge_stats_kernel(const unsigned* __restrict__ partial,
                                   unsigned* __restrict__ table,
                                   Scalars* sc) {
    const int k = blockIdx.x;
    const size_t b0 = (size_t)k * BITEMS;
    double sum = 0.0, ns = 0.0;
    for (int i = threadIdx.x; i < BITEMS; i += 1024) {
        size_t g = b0 + i;
        if (g < (size_t)kNumItems) {
            unsigned e = partial[g] + partial[(size_t)K2 * BITEMS + g];
            table[g] = e;
            unsigned c = e >> kCntShift;
            if (c) {
                float sf = (float)(e & kFixMask) * INV_FIX19;
                sum += (double)(sf / (float)c);
                ns += 1.0;
            }
        }
    }
    sum = blockReduceSum(sum);
    ns  = blockReduceSum(ns);
    if (threadIdx.x == 0) {
        unsafeAtomicAdd(&sc->sum_avg, sum);
        unsafeAtomicAdd(&sc->n_seen, ns);
    }
}

// ---------------- fallback path (small-workspace safety net) ---------------

__global__ void accum_fb_kernel(const float* __restrict__ rating,
                                const int* __restrict__ item,
                                unsigned* __restrict__ tabs,
                                int B, int lo, int hi) {
    unsigned* tab = tabs + (size_t)xcd_id() * kNumItems;
    int i4 = (blockIdx.x * blockDim.x + threadIdx.x) * 4;
    if (i4 + 3 < B) {
        intv4   it = __builtin_nontemporal_load((const intv4*)(item + i4));
        floatv4 r  = __builtin_nontemporal_load((const floatv4*)(rating + i4));
        int k[4] = {it.x, it.y, it.z, it.w};
        float rr[4] = {r.x, r.y, r.z, r.w};
#pragma unroll
        for (int q = 0; q < 4; ++q)
            if (k[q] >= lo && k[q] < hi) {
                unsigned enc = (unsigned)(rr[q] * FIX19) +
                               (rr[q] > 0.0f ? (1u << kCntShift) : 0u);
                __hip_atomic_fetch_add(tab + k[q], enc, __ATOMIC_RELAXED,
                                       __HIP_MEMORY_SCOPE_WORKGROUP);
            }
    } else {
        for (int i = i4; i < B; ++i)
            if (item[i] >= lo && item[i] < hi) {
                unsigned enc = (unsigned)(rating[i] * FIX19) +
                               (rating[i] > 0.0f ? (1u << kCntShift) : 0u);
                __hip_atomic_fetch_add(tab + item[i], enc, __ATOMIC_RELAXED,
                                       __HIP_MEMORY_SCOPE_WORKGROUP);
            }
    }
}

__global__ void merge_fb_kernel(unsigned* __restrict__ tabs, Scalars* sc, int n) {
    int i = blockIdx.x * blockDim.x + threadIdx.x;
    double sum = 0.0, ns = 0.0;
    if (i < n) {
        unsigned long long t = 0;
#pragma unroll
        for (int x = 0; x < kXCD; ++x)
            t += tabs[(size_t)x * kNumItems + i];
        unsigned e = (unsigned)t;
        tabs[i] = e;
        unsigned c = e >> kCntShift;
        if (c) {
            float sf = (float)(e & kFixMask) * INV_FIX19;
            sum = (double)(sf / (float)c);
            ns = 1.0;
        }
    }
    sum = blockReduceSum(sum);
    ns  = blockReduceSum(ns);
    if (threadIdx.x == 0) {
        unsafeAtomicAdd(&sc->sum_avg, sum);
        unsafeAtomicAdd(&sc->n_seen, ns);
    }
}

// ---------------- shared epilogue ------------------------------------------

__device__ __forceinline__ float decode_pred(unsigned e, float gmf) {
    unsigned c = e >> kCntShift;
    float sf = (float)(e & kFixMask) * INV_FIX19;
    return c ? sf / ((float)c + EPSF) : gmf;
}

// 16 targets/thread (proven sweet spot, VGPR ~28): issue all 8 stream loads +
// all 16 table gathers before any use. Loss partial goes to a plain per-block
// store (lossp), NOT a contended atomic (round-7 lesson).
__global__ void pred_kernel(const unsigned* __restrict__ tab,
                            const int* __restrict__ titem,
                            const float* __restrict__ trat,
                            float* __restrict__ out,
                            double* __restrict__ lossp,
                            const Scalars* __restrict__ sc,
                            int T) {
    const float gmf = (float)(sc->sum_avg / fmax(sc->n_seen, 1.0));
    const int t0 = (blockIdx.x * blockDim.x + threadIdx.x) * 16;
    double l = 0.0;
    if (t0 + 15 < T) {
        intv4 it0 = __builtin_nontemporal_load((const intv4*)(titem + t0));
        intv4 it1 = __builtin_nontemporal_load((const intv4*)(titem + t0 + 4));
        intv4 it2 = __builtin_nontemporal_load((const intv4*)(titem + t0 + 8));
        intv4 it3 = __builtin_nontemporal_load((const intv4*)(titem + t0 + 12));
        floatv4 r0 = __builtin_nontemporal_load((const floatv4*)(trat + t0));
        floatv4 r1 = __builtin_nontemporal_load((const floatv4*)(trat + t0 + 4));
        floatv4 r2 = __builtin_nontemporal_load((const floatv4*)(trat + t0 + 8));
        floatv4 r3 = __builtin_nontemporal_load((const floatv4*)(trat + t0 + 12));
        // 16 independent gathers in flight
        unsigned e0  = tab[(unsigned)it0.x];
        unsigned e1  = tab[(unsigned)it0.y];
        unsigned e2  = tab[(unsigned)it0.z];
        unsigned e3  = tab[(unsigned)it0.w];
        unsigned e4  = tab[(unsigned)it1.x];
        unsigned e5  = tab[(unsigned)it1.y];
        unsigned e6  = tab[(unsigned)it1.z];
        unsigned e7  = tab[(unsigned)it1.w];
        unsigned e8  = tab[(unsigned)it2.x];
        unsigned e9  = tab[(unsigned)it2.y];
        unsigned e10 = tab[(unsigned)it2.z];
        unsigned e11 = tab[(unsigned)it2.w];
        unsigned e12 = tab[(unsigned)it3.x];
        unsigned e13 = tab[(unsigned)it3.y];
        unsigned e14 = tab[(unsigned)it3.z];
        unsigned e15 = tab[(unsigned)it3.w];
        floatv4 p0, p1, p2, p3;
        p0.x = decode_pred(e0,  gmf);
        p0.y = decode_pred(e1,  gmf);
        p0.z = decode_pred(e2,  gmf);
        p0.w = decode_pred(e3,  gmf);
        p1.x = decode_pred(e4,  gmf);
        p1.y = decode_pred(e5,  gmf);
        p1.z = decode_pred(e6,  gmf);
        p1.w = decode_pred(e7,  gmf);
        p2.x = decode_pred(e8,  gmf);
        p2.y = decode_pred(e9,  gmf);
        p2.z = decode_pred(e10, gmf);
        p2.w = decode_pred(e11, gmf);
        p3.x = decode_pred(e12, gmf);
        p3.y = decode_pred(e13, gmf);
        p3.z = decode_pred(e14, gmf);
        p3.w = decode_pred(e15, gmf);
        __builtin_nontemporal_store(p0, (floatv4*)(out + t0));
        __builtin_nontemporal_store(p1, (floatv4*)(out + t0 + 4));
        __builtin_nontemporal_store(p2, (floatv4*)(out + t0 + 8));
        __builtin_nontemporal_store(p3, (floatv4*)(out + t0 + 12));
        double d;
        d = (double)p0.x - (double)r0.x; l += d * d;
        d = (double)p0.y - (double)r0.y; l += d * d;
        d = (double)p0.z - (double)r0.z; l += d * d;
        d = (double)p0.w - (double)r0.w; l += d * d;
        d = (double)p1.x - (double)r1.x; l += d * d;
        d = (double)p1.y - (double)r1.y; l += d * d;
        d = (double)p1.z - (double)r1.z; l += d * d;
        d = (double)p1.w - (double)r1.w; l += d * d;
        d = (double)p2.x - (double)r2.x; l += d * d;
        d = (double)p2.y - (double)r2.y; l += d * d;
        d = (double)p2.z - (double)r2.z; l += d * d;
        d = (double)p2.w - (double)r2.w; l += d * d;
        d = (double)p3.x - (double)r3.x; l += d * d;
        d = (double)p3.y - (double)r3.y; l += d * d;
        d = (double)p3.z - (double)r3.z; l += d * d;
        d = (double)p3.w - (double)r3.w; l += d * d;
    } else {
        for (int i = t0; i < T; ++i) {
            float p = decode_pred(tab[(unsigned)titem[i]], gmf);
            out[i] = p;
            double d = (double)p - (double)trat[i];
            l += d * d;
        }
    }
    l = blockReduceSum(l);
    if (threadIdx.x == 0) lossp[blockIdx.x] = l;
}

// single block: reduce per-block loss partials, emit mean loss.
__global__ void finalize_kernel(const double* __restrict__ lossp, int n,
                                float* __restrict__ out_loss, int T) {
    double l = 0.0;
    for (int i = threadIdx.x; i < n; i += 1024)
        l += lossp[i];
    l = blockReduceSum(l);
    if (threadIdx.x == 0)
        out_loss[0] = (float)(l / (double)T);
}

extern "C" void kernel_launch(void* const* d_in, const int* in_sizes, int n_in,
                              void* d_out, int out_size, void* d_ws, size_t ws_size,
                              hipStream_t stream) {
    const float* rating = (const float*)d_in[0];
    const int*   item   = (const int*)d_in[1];
    const int*   titem  = (const int*)d_in[2];
    const float* trat   = (const float*)d_in[3];
    const int B = in_sizes[0];
    const int T = in_sizes[2];
    const int NI = kNumItems;
    const int BLK = 256;
    float* out = (float*)d_out;
    const int gPred = ((T + 15) / 16 + BLK - 1) / BLK;

    // fast-path workspace layout (u32 units)
    size_t u = 0;
    unsigned* pairs   = (unsigned*)d_ws + 0;  u += (size_t)K2 * P * CAP;   // 67MB
    unsigned* cnt     = (unsigned*)d_ws + u;  u += (size_t)K2 * P;         // 512KB
    unsigned* partial = (unsigned*)d_ws + u;  u += (size_t)2 * K2 * BITEMS;// 8.4MB
    unsigned* table   = (unsigned*)d_ws + u;  u += (size_t)NI;             // 4MB
    size_t lp_off = ((u * 4 + 7) / 8) * 8;
    double* lossp = (double*)((char*)d_ws + lp_off);
    size_t sc_off = lp_off + (size_t)gPred * sizeof(double);
    Scalars* sc = (Scalars*)((char*)d_ws + sc_off);
    const size_t needed = sc_off + sizeof(Scalars);

    const bool fast = (ws_size >= needed) && (B <= P * CHUNK);

    if (fast) {
        // sc zeroed by scatter block 0 (no memset dispatch)
        scatter_kernel<<<P, SBLK, 0, stream>>>(item, rating, cnt, pairs, B, sc);
        bucket_accum_kernel<<<2 * K2, 1024, 0, stream>>>(pairs, cnt, partial);
        merge_stats_kernel<<<K2, 1024, 0, stream>>>(partial, table, sc);
        pred_kernel<<<gPred, BLK, 0, stream>>>(table, titem, trat,
                                               out, lossp, sc, T);
        finalize_kernel<<<1, 1024, 0, stream>>>(lossp, gPred, out + T, T);
    } else {
        unsigned* tabs = (unsigned*)d_ws;
        double* lossp2 = (double*)((char*)d_ws +
                                   (size_t)kXCD * NI * sizeof(unsigned));
        Scalars* sc2 = (Scalars*)((char*)lossp2 + (size_t)gPred * sizeof(double));
        (void)hipMemsetAsync(d_ws, 0,
                             (size_t)kXCD * NI * sizeof(unsigned) +
                             (size_t)gPred * sizeof(double) + sizeof(Scalars),
                             stream);
        const int gAcc = ((B + 3) / 4 + BLK - 1) / BLK;
        accum_fb_kernel<<<gAcc, BLK, 0, stream>>>(rating, item, tabs, B, 0, NI / 2);
        accum_fb_kernel<<<gAcc, BLK, 0, stream>>>(rating, item, tabs, B, NI / 2, NI);
        merge_fb_kernel<<<(NI + BLK - 1) / BLK, BLK, 0, stream>>>(tabs, sc2, NI);
        pred_kernel<<<gPred, BLK, 0, stream>>>(tabs, titem, trat,
                                               out, lossp2, sc2, T);
        finalize_kernel<<<1, 1024, 0, stream>>>(lossp2, gPred, out + T, T);
    }
}

// Round 11
// 245.278 us; speedup vs baseline: 1.0639x; 1.0243x over previous
//
#include <hip/hip_runtime.h>

constexpr int kNumItems = 1000000;
constexpr int kXCD = 8;
// ---- fast-path config ----
constexpr int K2     = 256;    // buckets: item >> 12
constexpr int BSH    = 12;
constexpr int BITEMS = 4096;   // items per bucket (256*4096 >= 1M)
constexpr int P      = 512;    // chunks
constexpr int CHUNK  = 16384;  // P*CHUNK = 2^23 = B
constexpr int SBLK   = 1024;   // scatter block threads (R11: 512->1024)
constexpr int CSTG   = 64;     // staging slots/bucket (R11: 48->64, 4 groups)
constexpr int CAP    = 128;    // fixed slot per (block,bucket): mean 64 + 8 sigma
constexpr unsigned kCntShift = 26;
constexpr unsigned kFixMask  = (1u << 26) - 1u;
#define EPSF 1e-10f
#define FIX19 524288.0f            // 2^19 fixed-point rating scale
#define INV_FIX19 (1.0f / 524288.0f)

typedef int   __attribute__((ext_vector_type(4))) intv4;
typedef float __attribute__((ext_vector_type(4))) floatv4;

struct Scalars {
    double sum_avg;
    double n_seen;
};

// ---------------------------------------------------------------------------
// Session lessons (keep; these shaped the structure):
//  * R2: atomicAdd-WITH-RETURN over 256 hot global addresses = serial
//    cross-XCD round-trip chain (462us). No atomic returns on hot paths.
//  * R3: pred at 32 elems/thread spilled (VGPR 44, WRITE 51->116MB), 120us.
//    16 elems/thread (VGPR ~28) is the MLP sweet spot.
//  * R5: L1-bypass gathers in pred: neutral. pred ~70us is L2/L3-side
//    random-line throughput, not L1 miss tracking.
//  * R6: fire-and-forget global atomics under streaming churn = write-through
//    storm (WRITE 131MB/pass, 164us/pass). Accumulate in LDS; write each
//    table line exactly once.
//  * R7: per-block f64 atomics to ONE cache line serialize at ~12.5ns each.
//    Grid-wide scalar reductions: <=O(100) atomic blocks or two-stage
//    plain-store reduction.
//  * R8 analysis: pred = 8.39M random gathers = 121G 64B-line-fills/s
//    (~7.7TB/s L3->L2) — at the Infinity-Cache random-line rate. Structurally
//    parked at ~69us.
//  * R9: (a) software-pipelining scatter loads: neutral (compiler already
//    hoists); (b) NT stores on re-read-soon data: regression. NT only for
//    write-once-read-never.
//  * R10: pairs [p][k][CAP] transposed layout: +2.5us (write locality).
//  * R11: scatter occupancy 16->32 waves/CU (SBLK 1024, CSTG 64) + rounds
//    8->4 (half the barriers/flush scans). Ring safety: leftover(<16) +
//    round incoming (mean 16, sigma 4) <= 64 is an +8-sigma bound.
// ---------------------------------------------------------------------------

__device__ __forceinline__ unsigned xcd_id() {
    return __builtin_amdgcn_s_getreg((31u << 11) | 20u) & 7u;
}

__device__ __forceinline__ double blockReduceSum(double v) {
    for (int off = 32; off > 0; off >>= 1)
        v += __shfl_down(v, off, 64);
    __shared__ double s[16];
    __syncthreads();
    const int lane = threadIdx.x & 63;
    const int wave = threadIdx.x >> 6;
    if (lane == 0) s[wave] = v;
    __syncthreads();
    const int nwaves = (blockDim.x + 63) >> 6;
    v = (threadIdx.x < nwaves) ? s[threadIdx.x] : 0.0;
    if (wave == 0) {
        for (int off = 8; off > 0; off >>= 1)
            v += __shfl_down(v, off, 64);
    }
    return v;
}

// pair layout: idx[31:20] (item within bucket) | countbit[19] | fix[18:0]
// zero pair == no-op (add decodes to 0), so zero padding is harmless.
__device__ __forceinline__ unsigned pack_pair(int item, float r) {
    unsigned fix = (unsigned)(r * FIX19);          // r in [0,1): fits 19 bits
    unsigned cb  = (r > 0.0f) ? (1u << 19) : 0u;
    return ((unsigned)(item & (BITEMS - 1)) << 20) | cb | fix;
}

// LDS write-combining scatter: stage pairs per bucket, flush complete
// 16-element (64B) groups into the block's OWN contiguous 128KB window
// pairs[p][k][CAP] (R10). R11: 1024 threads, 64-slot ring, 4 rounds.
__global__ void scatter_kernel(const int* __restrict__ item,
                               const float* __restrict__ rating,
                               unsigned* __restrict__ cnt,
                               unsigned* __restrict__ pairs, int B,
                               Scalars* sc) {
    __shared__ unsigned stage[K2][CSTG];   // 64KB
    __shared__ unsigned fill[K2];
    __shared__ unsigned flushed[K2];       // 16-groups flushed
    const int p = blockIdx.x;
    if (p == 0 && threadIdx.x == 0) {      // ordered before merge_stats
        sc->sum_avg = 0.0;
        sc->n_seen = 0.0;
    }
    for (int k = threadIdx.x; k < K2; k += SBLK) {
        fill[k] = 0;
        flushed[k] = 0;
    }
    __syncthreads();
    const int base = p * CHUNK;
    const int f16 = threadIdx.x >> 4;      // 64 flushers of 16 lanes
    const int lane16 = threadIdx.x & 15;
#pragma unroll 1
    for (int j = 0; j < CHUNK / (SBLK * 4); ++j) {   // 4 rounds x 4096 elems
        int e = base + j * (SBLK * 4) + threadIdx.x * 4;
        if (e + 3 < B) {
            intv4   it = __builtin_nontemporal_load((const intv4*)(item + e));
            floatv4 r  = __builtin_nontemporal_load((const floatv4*)(rating + e));
            int k; unsigned s;
            k = it.x >> BSH; s = atomicAdd(&fill[k], 1u); stage[k][s % CSTG] = pack_pair(it.x, r.x);
            k = it.y >> BSH; s = atomicAdd(&fill[k], 1u); stage[k][s % CSTG] = pack_pair(it.y, r.y);
            k = it.z >> BSH; s = atomicAdd(&fill[k], 1u); stage[k][s % CSTG] = pack_pair(it.z, r.z);
            k = it.w >> BSH; s = atomicAdd(&fill[k], 1u); stage[k][s % CSTG] = pack_pair(it.w, r.w);
        } else {
            for (int q = e; q < B && q < e + 4; ++q) {
                int k = item[q] >> BSH;
                unsigned s = atomicAdd(&fill[k], 1u);
                stage[k][s % CSTG] = pack_pair(item[q], rating[q]);
            }
        }
        __syncthreads();
        // flush all complete 16-groups (leftover < 16 per bucket afterwards).
        // groups beyond CAP are consumed from the ring but dropped (~never).
        for (int b = 0; b < K2 / 64; ++b) {
            int k = f16 + (b << 6);
            unsigned f = fill[k];
            unsigned g = flushed[k];
            size_t rb = ((size_t)p * K2 + k) * CAP;   // block-local window
            while ((g + 1) * 16 <= f) {
                unsigned sbase = (g * 16) % CSTG;     // {0,16,32,48}: no wrap
                unsigned v = stage[k][sbase + lane16];
                if (g * 16 < (unsigned)CAP)
                    pairs[rb + g * 16 + lane16] = v;
                ++g;
            }
            if (lane16 == 0) flushed[k] = g;
        }
        __syncthreads();
    }
    // final partial group, zero-padded to 16 (zero pairs are no-ops)
    for (int b = 0; b < K2 / 64; ++b) {
        int k = f16 + (b << 6);
        unsigned f = fill[k];
        unsigned g = flushed[k];
        if (g * 16 < f && g * 16 < (unsigned)CAP) {
            size_t rb = ((size_t)p * K2 + k) * CAP;
            unsigned sbase = (g * 16) % CSTG;
            unsigned idx = g * 16 + lane16;
            unsigned v = (idx < f) ? stage[k][sbase + lane16] : 0u;
            pairs[rb + idx] = v;
        }
    }
    // per-(k,p) valid counts for the accum prefix reads
    for (int k = threadIdx.x; k < K2; k += SBLK)
        cnt[(size_t)k * P + p] = min(fill[k], (unsigned)CAP);
}

// two blocks per bucket (p-halves): wave-per-segment prefix reads (256B
// contiguous per wave), LDS integer histogram (bit-exact), plain coalesced
// partial-hist write. NO global atomics (round-6 lesson).
__global__ void bucket_accum_kernel(const unsigned* __restrict__ pairs,
                                    const unsigned* __restrict__ cnt,
                                    unsigned* __restrict__ partial) {
    __shared__ unsigned hist[BITEMS];      // 16KB
    __shared__ unsigned cnl[P / 2];
    const int k = blockIdx.x >> 1;
    const int h = blockIdx.x & 1;
    for (int i = threadIdx.x; i < BITEMS; i += 1024) hist[i] = 0;
    if (threadIdx.x < P / 2)
        cnl[threadIdx.x] = cnt[(size_t)k * P + h * (P / 2) + threadIdx.x];
    __syncthreads();
    const int wave = threadIdx.x >> 6;
    const int lane = threadIdx.x & 63;
    for (int q = wave; q < P / 2; q += 16) {
        int p = h * (P / 2) + q;
        unsigned n = cnl[q];                       // wave-uniform (broadcast)
        size_t rb = ((size_t)p * K2 + k) * CAP;    // R10 transposed layout
        for (unsigned i = lane; i < n; i += 64) {
            unsigned v = __builtin_nontemporal_load(pairs + rb + i);
            if (v) {
                unsigned add = ((v & (1u << 19)) << 7) | (v & 0x7FFFFu);
                atomicAdd(&hist[v >> 20], add);
            }
        }
    }
    __syncthreads();
    unsigned* dst = partial + ((size_t)h * K2 + k) * BITEMS;
    for (int i = threadIdx.x; i < BITEMS; i += 1024)
        __builtin_nontemporal_store(hist[i], dst + i);
}

// K2 blocks x 1024 threads: sum the two partial halves -> final table
// (written exactly once), fused global-mean partials. Only 512 contended
// atomics total (round-7 lesson: keep atomic blocks O(100)).
__global__ void merge_stats_kernel(const unsigned* __restrict__ partial,
                                   unsigned* __restrict__ table,
                                   Scalars* sc) {
    const int k = blockIdx.x;
    const size_t b0 = (size_t)k * BITEMS;
    double sum = 0.0, ns = 0.0;
    for (int i = threadIdx.x; i < BITEMS; i += 1024) {
        size_t g = b0 + i;
        if (g < (size_t)kNumItems) {
            unsigned e = partial[g] + partial[(size_t)K2 * BITEMS + g];
            table[g] = e;
            unsigned c = e >> kCntShift;
            if (c) {
                float sf = (float)(e & kFixMask) * INV_FIX19;
                sum += (double)(sf / (float)c);
                ns += 1.0;
            }
        }
    }
    sum = blockReduceSum(sum);
    ns  = blockReduceSum(ns);
    if (threadIdx.x == 0) {
        unsafeAtomicAdd(&sc->sum_avg, sum);
        unsafeAtomicAdd(&sc->n_seen, ns);
    }
}

// ---------------- fallback path (small-workspace safety net) ---------------

__global__ void accum_fb_kernel(const float* __restrict__ rating,
                                const int* __restrict__ item,
                                unsigned* __restrict__ tabs,
                                int B, int lo, int hi) {
    unsigned* tab = tabs + (size_t)xcd_id() * kNumItems;
    int i4 = (blockIdx.x * blockDim.x + threadIdx.x) * 4;
    if (i4 + 3 < B) {
        intv4   it = __builtin_nontemporal_load((const intv4*)(item + i4));
        floatv4 r  = __builtin_nontemporal_load((const floatv4*)(rating + i4));
        int k[4] = {it.x, it.y, it.z, it.w};
        float rr[4] = {r.x, r.y, r.z, r.w};
#pragma unroll
        for (int q = 0; q < 4; ++q)
            if (k[q] >= lo && k[q] < hi) {
                unsigned enc = (unsigned)(rr[q] * FIX19) +
                               (rr[q] > 0.0f ? (1u << kCntShift) : 0u);
                __hip_atomic_fetch_add(tab + k[q], enc, __ATOMIC_RELAXED,
                                       __HIP_MEMORY_SCOPE_WORKGROUP);
            }
    } else {
        for (int i = i4; i < B; ++i)
            if (item[i] >= lo && item[i] < hi) {
                unsigned enc = (unsigned)(rating[i] * FIX19) +
                               (rating[i] > 0.0f ? (1u << kCntShift) : 0u);
                __hip_atomic_fetch_add(tab + item[i], enc, __ATOMIC_RELAXED,
                                       __HIP_MEMORY_SCOPE_WORKGROUP);
            }
    }
}

__global__ void merge_fb_kernel(unsigned* __restrict__ tabs, Scalars* sc, int n) {
    int i = blockIdx.x * blockDim.x + threadIdx.x;
    double sum = 0.0, ns = 0.0;
    if (i < n) {
        unsigned long long t = 0;
#pragma unroll
        for (int x = 0; x < kXCD; ++x)
            t += tabs[(size_t)x * kNumItems + i];
        unsigned e = (unsigned)t;
        tabs[i] = e;
        unsigned c = e >> kCntShift;
        if (c) {
            float sf = (float)(e & kFixMask) * INV_FIX19;
            sum = (double)(sf / (float)c);
            ns = 1.0;
        }
    }
    sum = blockReduceSum(sum);
    ns  = blockReduceSum(ns);
    if (threadIdx.x == 0) {
        unsafeAtomicAdd(&sc->sum_avg, sum);
        unsafeAtomicAdd(&sc->n_seen, ns);
    }
}

// ---------------- shared epilogue ------------------------------------------

__device__ __forceinline__ float decode_pred(unsigned e, float gmf) {
    unsigned c = e >> kCntShift;
    float sf = (float)(e & kFixMask) * INV_FIX19;
    return c ? sf / ((float)c + EPSF) : gmf;
}

// 16 targets/thread (proven sweet spot, VGPR ~28): issue all 8 stream loads +
// all 16 table gathers before any use. Loss partial goes to a plain per-block
// store (lossp), NOT a contended atomic (round-7 lesson).
__global__ void pred_kernel(const unsigned* __restrict__ tab,
                            const int* __restrict__ titem,
                            const float* __restrict__ trat,
                            float* __restrict__ out,
                            double* __restrict__ lossp,
                            const Scalars* __restrict__ sc,
                            int T) {
    const float gmf = (float)(sc->sum_avg / fmax(sc->n_seen, 1.0));
    const int t0 = (blockIdx.x * blockDim.x + threadIdx.x) * 16;
    double l = 0.0;
    if (t0 + 15 < T) {
        intv4 it0 = __builtin_nontemporal_load((const intv4*)(titem + t0));
        intv4 it1 = __builtin_nontemporal_load((const intv4*)(titem + t0 + 4));
        intv4 it2 = __builtin_nontemporal_load((const intv4*)(titem + t0 + 8));
        intv4 it3 = __builtin_nontemporal_load((const intv4*)(titem + t0 + 12));
        floatv4 r0 = __builtin_nontemporal_load((const floatv4*)(trat + t0));
        floatv4 r1 = __builtin_nontemporal_load((const floatv4*)(trat + t0 + 4));
        floatv4 r2 = __builtin_nontemporal_load((const floatv4*)(trat + t0 + 8));
        floatv4 r3 = __builtin_nontemporal_load((const floatv4*)(trat + t0 + 12));
        // 16 independent gathers in flight
        unsigned e0  = tab[(unsigned)it0.x];
        unsigned e1  = tab[(unsigned)it0.y];
        unsigned e2  = tab[(unsigned)it0.z];
        unsigned e3  = tab[(unsigned)it0.w];
        unsigned e4  = tab[(unsigned)it1.x];
        unsigned e5  = tab[(unsigned)it1.y];
        unsigned e6  = tab[(unsigned)it1.z];
        unsigned e7  = tab[(unsigned)it1.w];
        unsigned e8  = tab[(unsigned)it2.x];
        unsigned e9  = tab[(unsigned)it2.y];
        unsigned e10 = tab[(unsigned)it2.z];
        unsigned e11 = tab[(unsigned)it2.w];
        unsigned e12 = tab[(unsigned)it3.x];
        unsigned e13 = tab[(unsigned)it3.y];
        unsigned e14 = tab[(unsigned)it3.z];
        unsigned e15 = tab[(unsigned)it3.w];
        floatv4 p0, p1, p2, p3;
        p0.x = decode_pred(e0,  gmf);
        p0.y = decode_pred(e1,  gmf);
        p0.z = decode_pred(e2,  gmf);
        p0.w = decode_pred(e3,  gmf);
        p1.x = decode_pred(e4,  gmf);
        p1.y = decode_pred(e5,  gmf);
        p1.z = decode_pred(e6,  gmf);
        p1.w = decode_pred(e7,  gmf);
        p2.x = decode_pred(e8,  gmf);
        p2.y = decode_pred(e9,  gmf);
        p2.z = decode_pred(e10, gmf);
        p2.w = decode_pred(e11, gmf);
        p3.x = decode_pred(e12, gmf);
        p3.y = decode_pred(e13, gmf);
        p3.z = decode_pred(e14, gmf);
        p3.w = decode_pred(e15, gmf);
        __builtin_nontemporal_store(p0, (floatv4*)(out + t0));
        __builtin_nontemporal_store(p1, (floatv4*)(out + t0 + 4));
        __builtin_nontemporal_store(p2, (floatv4*)(out + t0 + 8));
        __builtin_nontemporal_store(p3, (floatv4*)(out + t0 + 12));
        double d;
        d = (double)p0.x - (double)r0.x; l += d * d;
        d = (double)p0.y - (double)r0.y; l += d * d;
        d = (double)p0.z - (double)r0.z; l += d * d;
        d = (double)p0.w - (double)r0.w; l += d * d;
        d = (double)p1.x - (double)r1.x; l += d * d;
        d = (double)p1.y - (double)r1.y; l += d * d;
        d = (double)p1.z - (double)r1.z; l += d * d;
        d = (double)p1.w - (double)r1.w; l += d * d;
        d = (double)p2.x - (double)r2.x; l += d * d;
        d = (double)p2.y - (double)r2.y; l += d * d;
        d = (double)p2.z - (double)r2.z; l += d * d;
        d = (double)p2.w - (double)r2.w; l += d * d;
        d = (double)p3.x - (double)r3.x; l += d * d;
        d = (double)p3.y - (double)r3.y; l += d * d;
        d = (double)p3.z - (double)r3.z; l += d * d;
        d = (double)p3.w - (double)r3.w; l += d * d;
    } else {
        for (int i = t0; i < T; ++i) {
            float p = decode_pred(tab[(unsigned)titem[i]], gmf);
            out[i] = p;
            double d = (double)p - (double)trat[i];
            l += d * d;
        }
    }
    l = blockReduceSum(l);
    if (threadIdx.x == 0) lossp[blockIdx.x] = l;
}

// single block: reduce per-block loss partials, emit mean loss.
__global__ void finalize_kernel(const double* __restrict__ lossp, int n,
                                float* __restrict__ out_loss, int T) {
    double l = 0.0;
    for (int i = threadIdx.x; i < n; i += 1024)
        l += lossp[i];
    l = blockReduceSum(l);
    if (threadIdx.x == 0)
        out_loss[0] = (float)(l / (double)T);
}

extern "C" void kernel_launch(void* const* d_in, const int* in_sizes, int n_in,
                              void* d_out, int out_size, void* d_ws, size_t ws_size,
                              hipStream_t stream) {
    const float* rating = (const float*)d_in[0];
    const int*   item   = (const int*)d_in[1];
    const int*   titem  = (const int*)d_in[2];
    const float* trat   = (const float*)d_in[3];
    const int B = in_sizes[0];
    const int T = in_sizes[2];
    const int NI = kNumItems;
    const int BLK = 256;
    float* out = (float*)d_out;
    const int gPred = ((T + 15) / 16 + BLK - 1) / BLK;

    // fast-path workspace layout (u32 units)
    size_t u = 0;
    unsigned* pairs   = (unsigned*)d_ws + 0;  u += (size_t)K2 * P * CAP;   // 67MB
    unsigned* cnt     = (unsigned*)d_ws + u;  u += (size_t)K2 * P;         // 512KB
    unsigned* partial = (unsigned*)d_ws + u;  u += (size_t)2 * K2 * BITEMS;// 8.4MB
    unsigned* table   = (unsigned*)d_ws + u;  u += (size_t)NI;             // 4MB
    size_t lp_off = ((u * 4 + 7) / 8) * 8;
    double* lossp = (double*)((char*)d_ws + lp_off);
    size_t sc_off = lp_off + (size_t)gPred * sizeof(double);
    Scalars* sc = (Scalars*)((char*)d_ws + sc_off);
    const size_t needed = sc_off + sizeof(Scalars);

    const bool fast = (ws_size >= needed) && (B <= P * CHUNK);

    if (fast) {
        // sc zeroed by scatter block 0 (no memset dispatch)
        scatter_kernel<<<P, SBLK, 0, stream>>>(item, rating, cnt, pairs, B, sc);
        bucket_accum_kernel<<<2 * K2, 1024, 0, stream>>>(pairs, cnt, partial);
        merge_stats_kernel<<<K2, 1024, 0, stream>>>(partial, table, sc);
        pred_kernel<<<gPred, BLK, 0, stream>>>(table, titem, trat,
                                               out, lossp, sc, T);
        finalize_kernel<<<1, 1024, 0, stream>>>(lossp, gPred, out + T, T);
    } else {
        unsigned* tabs = (unsigned*)d_ws;
        double* lossp2 = (double*)((char*)d_ws +
                                   (size_t)kXCD * NI * sizeof(unsigned));
        Scalars* sc2 = (Scalars*)((char*)lossp2 + (size_t)gPred * sizeof(double));
        (void)hipMemsetAsync(d_ws, 0,
                             (size_t)kXCD * NI * sizeof(unsigned) +
                             (size_t)gPred * sizeof(double) + sizeof(Scalars),
                             stream);
        const int gAcc = ((B + 3) / 4 + BLK - 1) / BLK;
        accum_fb_kernel<<<gAcc, BLK, 0, stream>>>(rating, item, tabs, B, 0, NI / 2);
        accum_fb_kernel<<<gAcc, BLK, 0, stream>>>(rating, item, tabs, B, NI / 2, NI);
        merge_fb_kernel<<<(NI + BLK - 1) / BLK, BLK, 0, stream>>>(tabs, sc2, NI);
        pred_kernel<<<gPred, BLK, 0, stream>>>(tabs, titem, trat,
                                               out, lossp2, sc2, T);
        finalize_kernel<<<1, 1024, 0, stream>>>(lossp2, gPred, out + T, T);
    }
}